// Round 1
// baseline (535.090 us; speedup 1.0000x reference)
//
#include <hip/hip_runtime.h>

// Problem constants (powers of two -> shift/mask index math)
// B=32, C=3, H=512, W=512; H*W = 2^18, W = 2^9
#define IMG_B 32
#define IMG_C 3
#define IMG_H 512
#define IMG_W 512
#define HW_SHIFT 18
#define W_SHIFT 9

// d_ws layout: [0, 2304) : 64 inverted 3x3 matrices (32 pred, 32 true), 9 floats each
//              [2304, 2312): double accumulator
#define WS_INV_FLOATS (64 * 9)
#define WS_ACC_OFFSET (WS_INV_FLOATS * sizeof(float))

__global__ void photoloss_invert_kernel(const float* __restrict__ Hp,
                                        const float* __restrict__ Ht,
                                        float* __restrict__ ws_inv,
                                        double* __restrict__ acc) {
    int t = threadIdx.x;
    if (t == 0) *acc = 0.0;  // ws is poisoned 0xAA before every launch
    if (t < 64) {
        const float* src = (t < 32) ? (Hp + t * 9) : (Ht + (t - 32) * 9);
        float* dst = ws_inv + t * 9;
        // 3x3 inverse via adjugate, computed in double for conditioning
        double a = src[0], b = src[1], c = src[2];
        double d = src[3], e = src[4], f = src[5];
        double g = src[6], h = src[7], i = src[8];
        double A = e * i - f * h;
        double Bc = c * h - b * i;
        double Cc = b * f - c * e;
        double D = f * g - d * i;
        double E = a * i - c * g;
        double F = c * d - a * f;
        double G = d * h - e * g;
        double Hh = b * g - a * h;
        double Ii = a * e - b * d;
        double idet = 1.0 / (a * A + b * D + c * G);
        dst[0] = (float)(A * idet);
        dst[1] = (float)(Bc * idet);
        dst[2] = (float)(Cc * idet);
        dst[3] = (float)(D * idet);
        dst[4] = (float)(E * idet);
        dst[5] = (float)(F * idet);
        dst[6] = (float)(G * idet);
        dst[7] = (float)(Hh * idet);
        dst[8] = (float)(Ii * idet);
    }
}

__device__ __forceinline__ float fetch_px(const float* __restrict__ img, int xi, int yi) {
    // zero padding outside [0,512)x[0,512); unsigned compare handles negatives
    if ((unsigned)xi < (unsigned)IMG_W && (unsigned)yi < (unsigned)IMG_H)
        return img[(yi << W_SHIFT) + xi];
    return 0.0f;
}

__global__ __launch_bounds__(256) void photoloss_main_kernel(
        const float* __restrict__ I,
        const float* __restrict__ ws_inv,
        double* __restrict__ acc) {
    const int b = blockIdx.y;
    const int p = blockIdx.x * 256 + threadIdx.x;  // pixel index within image, < 2^18
    const int y = p >> W_SHIFT;
    const int x = p & (IMG_W - 1);

    const float* __restrict__ hp = ws_inv + b * 9;          // pred inverse
    const float* __restrict__ ht = ws_inv + (b + 32) * 9;   // true inverse

    const float fx = (float)x, fy = (float)y;

    // ---- pred grid ----
    float Xp = hp[0] * fx + hp[1] * fy + hp[2];
    float Yp = hp[3] * fx + hp[4] * fy + hp[5];
    float Zp = hp[6] * fx + hp[7] * fy + hp[8];
    float izp = 1.0f / Zp;
    Xp *= izp; Yp *= izp;
    // reference: x_norm = 2X/(W-1)-1 ; x_pix = ((x_norm+1)*W-1)*0.5
    float xnp = 2.0f * Xp / (float)(IMG_W - 1) - 1.0f;
    float ynp = 2.0f * Yp / (float)(IMG_H - 1) - 1.0f;
    float xsp = ((xnp + 1.0f) * (float)IMG_W - 1.0f) * 0.5f;
    float ysp = ((ynp + 1.0f) * (float)IMG_H - 1.0f) * 0.5f;

    float x0fp = floorf(xsp), y0fp = floorf(ysp);
    int x0p = (int)x0fp, y0p = (int)y0fp;
    int x1p = x0p + 1, y1p = y0p + 1;
    float wx1p = xsp - x0fp, wx0p = 1.0f - wx1p;
    float wy1p = ysp - y0fp, wy0p = 1.0f - wy1p;

    // ---- true grid ----
    float Xt = ht[0] * fx + ht[1] * fy + ht[2];
    float Yt = ht[3] * fx + ht[4] * fy + ht[5];
    float Zt = ht[6] * fx + ht[7] * fy + ht[8];
    float izt = 1.0f / Zt;
    Xt *= izt; Yt *= izt;
    float xnt = 2.0f * Xt / (float)(IMG_W - 1) - 1.0f;
    float ynt = 2.0f * Yt / (float)(IMG_H - 1) - 1.0f;
    float xst = ((xnt + 1.0f) * (float)IMG_W - 1.0f) * 0.5f;
    float yst = ((ynt + 1.0f) * (float)IMG_H - 1.0f) * 0.5f;

    float x0ft = floorf(xst), y0ft = floorf(yst);
    int x0t = (int)x0ft, y0t = (int)y0ft;
    int x1t = x0t + 1, y1t = y0t + 1;
    float wx1t = xst - x0ft, wx0t = 1.0f - wx1t;
    float wy1t = yst - y0ft, wy0t = 1.0f - wy1t;

    const float w00p = wx0p * wy0p, w10p = wx1p * wy0p, w01p = wx0p * wy1p, w11p = wx1p * wy1p;
    const float w00t = wx0t * wy0t, w10t = wx1t * wy0t, w01t = wx0t * wy1t, w11t = wx1t * wy1t;

    float lsum = 0.0f;
    const float* __restrict__ img = I + ((size_t)b * IMG_C << HW_SHIFT);
#pragma unroll
    for (int c = 0; c < IMG_C; ++c) {
        const float* __restrict__ ch = img + ((size_t)c << HW_SHIFT);
        float vp = fetch_px(ch, x0p, y0p) * w00p
                 + fetch_px(ch, x1p, y0p) * w10p
                 + fetch_px(ch, x0p, y1p) * w01p
                 + fetch_px(ch, x1p, y1p) * w11p;
        float vt = fetch_px(ch, x0t, y0t) * w00t
                 + fetch_px(ch, x1t, y0t) * w10t
                 + fetch_px(ch, x0t, y1t) * w01t
                 + fetch_px(ch, x1t, y1t) * w11t;
        float d = vp - vt;
        lsum += d * d;
    }

    // wave (64-lane) reduction
#pragma unroll
    for (int off = 32; off > 0; off >>= 1)
        lsum += __shfl_down(lsum, off, 64);

    __shared__ float wsum[4];
    const int lane = threadIdx.x & 63;
    const int wid = threadIdx.x >> 6;
    if (lane == 0) wsum[wid] = lsum;
    __syncthreads();
    if (threadIdx.x == 0) {
        float s = wsum[0] + wsum[1] + wsum[2] + wsum[3];
        atomicAdd(acc, (double)s);
    }
}

__global__ void photoloss_finalize_kernel(const double* __restrict__ acc,
                                          float* __restrict__ out) {
    const double n = (double)IMG_B * IMG_C * IMG_H * IMG_W;  // 25165824
    out[0] = (float)(*acc / n);
}

extern "C" void kernel_launch(void* const* d_in, const int* in_sizes, int n_in,
                              void* d_out, int out_size, void* d_ws, size_t ws_size,
                              hipStream_t stream) {
    const float* Hp = (const float*)d_in[0];
    const float* Ht = (const float*)d_in[1];
    const float* I  = (const float*)d_in[2];
    float* out = (float*)d_out;

    float* ws_inv = (float*)d_ws;
    double* acc = (double*)((char*)d_ws + WS_ACC_OFFSET);

    photoloss_invert_kernel<<<1, 64, 0, stream>>>(Hp, Ht, ws_inv, acc);

    dim3 grid(IMG_H * IMG_W / 256, IMG_B);  // (1024, 32)
    photoloss_main_kernel<<<grid, 256, 0, stream>>>(I, ws_inv, acc);

    photoloss_finalize_kernel<<<1, 1, 0, stream>>>(acc, out);
}

// Round 2
// 530.926 us; speedup vs baseline: 1.0078x; 1.0078x over previous
//
#include <hip/hip_runtime.h>

// Problem constants (powers of two -> shift/mask index math)
// B=32, C=3, H=512, W=512; H*W = 2^18, W = 2^9
#define IMG_B 32
#define IMG_C 3
#define IMG_H 512
#define IMG_W 512
#define HW_SHIFT 18
#define W_SHIFT 9

// d_ws layout: [0, 2304) : 64 inverted 3x3 matrices (32 pred, 32 true), 9 floats each
//              [2304, 2312): double accumulator
#define WS_INV_FLOATS (64 * 9)
#define WS_ACC_OFFSET (WS_INV_FLOATS * sizeof(float))

__global__ void photoloss_invert_kernel(const float* __restrict__ Hp,
                                        const float* __restrict__ Ht,
                                        float* __restrict__ ws_inv,
                                        double* __restrict__ acc) {
    int t = threadIdx.x;
    if (t == 0) *acc = 0.0;  // ws is poisoned 0xAA before every launch
    if (t < 64) {
        const float* src = (t < 32) ? (Hp + t * 9) : (Ht + (t - 32) * 9);
        float* dst = ws_inv + t * 9;
        // 3x3 inverse via adjugate, computed in double for conditioning
        double a = src[0], b = src[1], c = src[2];
        double d = src[3], e = src[4], f = src[5];
        double g = src[6], h = src[7], i = src[8];
        double A = e * i - f * h;
        double Bc = c * h - b * i;
        double Cc = b * f - c * e;
        double D = f * g - d * i;
        double E = a * i - c * g;
        double F = c * d - a * f;
        double G = d * h - e * g;
        double Hh = b * g - a * h;
        double Ii = a * e - b * d;
        double idet = 1.0 / (a * A + b * D + c * G);
        dst[0] = (float)(A * idet);
        dst[1] = (float)(Bc * idet);
        dst[2] = (float)(Cc * idet);
        dst[3] = (float)(D * idet);
        dst[4] = (float)(E * idet);
        dst[5] = (float)(F * idet);
        dst[6] = (float)(G * idet);
        dst[7] = (float)(Hh * idet);
        dst[8] = (float)(Ii * idet);
    }
}

// Compute clamped flat offset + validity-masked weight for one bilinear corner.
__device__ __forceinline__ void corner(int xi, int yi, float w,
                                       int& off, float& wout) {
    const bool valid = ((unsigned)xi < (unsigned)IMG_W) & ((unsigned)yi < (unsigned)IMG_H);
    const int xc = min(max(xi, 0), IMG_W - 1);
    const int yc = min(max(yi, 0), IMG_H - 1);
    off = (yc << W_SHIFT) + xc;
    wout = valid ? w : 0.0f;
}

__global__ __launch_bounds__(256) void photoloss_main_kernel(
        const float* __restrict__ I,
        const float* __restrict__ ws_inv,
        double* __restrict__ acc) {
    const int b = blockIdx.y;
    const int p = blockIdx.x * 256 + threadIdx.x;  // pixel index within image, < 2^18
    const int y = p >> W_SHIFT;
    const int x = p & (IMG_W - 1);

    const float* __restrict__ hp = ws_inv + b * 9;          // pred inverse
    const float* __restrict__ ht = ws_inv + (b + 32) * 9;   // true inverse

    const float fx = (float)x, fy = (float)y;

    // ---- pred grid ----
    float Xp = hp[0] * fx + hp[1] * fy + hp[2];
    float Yp = hp[3] * fx + hp[4] * fy + hp[5];
    float Zp = hp[6] * fx + hp[7] * fy + hp[8];
    float izp = 1.0f / Zp;
    Xp *= izp; Yp *= izp;
    // reference: x_norm = 2X/(W-1)-1 ; x_pix = ((x_norm+1)*W-1)*0.5
    float xnp = 2.0f * Xp / (float)(IMG_W - 1) - 1.0f;
    float ynp = 2.0f * Yp / (float)(IMG_H - 1) - 1.0f;
    float xsp = ((xnp + 1.0f) * (float)IMG_W - 1.0f) * 0.5f;
    float ysp = ((ynp + 1.0f) * (float)IMG_H - 1.0f) * 0.5f;

    float x0fp = floorf(xsp), y0fp = floorf(ysp);
    int x0p = (int)x0fp, y0p = (int)y0fp;
    int x1p = x0p + 1, y1p = y0p + 1;
    float wx1p = xsp - x0fp, wx0p = 1.0f - wx1p;
    float wy1p = ysp - y0fp, wy0p = 1.0f - wy1p;

    // ---- true grid ----
    float Xt = ht[0] * fx + ht[1] * fy + ht[2];
    float Yt = ht[3] * fx + ht[4] * fy + ht[5];
    float Zt = ht[6] * fx + ht[7] * fy + ht[8];
    float izt = 1.0f / Zt;
    Xt *= izt; Yt *= izt;
    float xnt = 2.0f * Xt / (float)(IMG_W - 1) - 1.0f;
    float ynt = 2.0f * Yt / (float)(IMG_H - 1) - 1.0f;
    float xst = ((xnt + 1.0f) * (float)IMG_W - 1.0f) * 0.5f;
    float yst = ((ynt + 1.0f) * (float)IMG_H - 1.0f) * 0.5f;

    float x0ft = floorf(xst), y0ft = floorf(yst);
    int x0t = (int)x0ft, y0t = (int)y0ft;
    int x1t = x0t + 1, y1t = y0t + 1;
    float wx1t = xst - x0ft, wx0t = 1.0f - wx1t;
    float wy1t = yst - y0ft, wy0t = 1.0f - wy1t;

    // 8 corners: [0..3] = pred (00,10,01,11), [4..7] = true
    int   offs[8];
    float wts[8];
    corner(x0p, y0p, wx0p * wy0p, offs[0], wts[0]);
    corner(x1p, y0p, wx1p * wy0p, offs[1], wts[1]);
    corner(x0p, y1p, wx0p * wy1p, offs[2], wts[2]);
    corner(x1p, y1p, wx1p * wy1p, offs[3], wts[3]);
    corner(x0t, y0t, wx0t * wy0t, offs[4], wts[4]);
    corner(x1t, y0t, wx1t * wy0t, offs[5], wts[5]);
    corner(x0t, y1t, wx0t * wy1t, offs[6], wts[6]);
    corner(x1t, y1t, wx1t * wy1t, offs[7], wts[7]);

    const float* __restrict__ img = I + ((size_t)b * IMG_C << HW_SHIFT);

    // Batch ALL 24 loads (unconditional, clamped addresses) before any use,
    // so the wave has maximal loads in flight behind one vmcnt wait.
    float v[IMG_C * 8];
#pragma unroll
    for (int c = 0; c < IMG_C; ++c) {
        const float* __restrict__ ch = img + ((size_t)c << HW_SHIFT);
#pragma unroll
        for (int k = 0; k < 8; ++k) {
            v[c * 8 + k] = ch[offs[k]];
        }
    }

    float lsum = 0.0f;
#pragma unroll
    for (int c = 0; c < IMG_C; ++c) {
        const float* vc = v + c * 8;
        float vp = vc[0] * wts[0] + vc[1] * wts[1] + vc[2] * wts[2] + vc[3] * wts[3];
        float vt = vc[4] * wts[4] + vc[5] * wts[5] + vc[6] * wts[6] + vc[7] * wts[7];
        float d = vp - vt;
        lsum += d * d;
    }

    // wave (64-lane) reduction
#pragma unroll
    for (int off = 32; off > 0; off >>= 1)
        lsum += __shfl_down(lsum, off, 64);

    __shared__ float wsum[4];
    const int lane = threadIdx.x & 63;
    const int wid = threadIdx.x >> 6;
    if (lane == 0) wsum[wid] = lsum;
    __syncthreads();
    if (threadIdx.x == 0) {
        float s = wsum[0] + wsum[1] + wsum[2] + wsum[3];
        atomicAdd(acc, (double)s);
    }
}

__global__ void photoloss_finalize_kernel(const double* __restrict__ acc,
                                          float* __restrict__ out) {
    const double n = (double)IMG_B * IMG_C * IMG_H * IMG_W;  // 25165824
    out[0] = (float)(*acc / n);
}

extern "C" void kernel_launch(void* const* d_in, const int* in_sizes, int n_in,
                              void* d_out, int out_size, void* d_ws, size_t ws_size,
                              hipStream_t stream) {
    const float* Hp = (const float*)d_in[0];
    const float* Ht = (const float*)d_in[1];
    const float* I  = (const float*)d_in[2];
    float* out = (float*)d_out;

    float* ws_inv = (float*)d_ws;
    double* acc = (double*)((char*)d_ws + WS_ACC_OFFSET);

    photoloss_invert_kernel<<<1, 64, 0, stream>>>(Hp, Ht, ws_inv, acc);

    dim3 grid(IMG_H * IMG_W / 256, IMG_B);  // (1024, 32)
    photoloss_main_kernel<<<grid, 256, 0, stream>>>(I, ws_inv, acc);

    photoloss_finalize_kernel<<<1, 1, 0, stream>>>(acc, out);
}

// Round 3
// 236.381 us; speedup vs baseline: 2.2637x; 2.2461x over previous
//
#include <hip/hip_runtime.h>

// Problem constants (powers of two -> shift/mask index math)
// B=32, C=3, H=512, W=512; H*W = 2^18, W = 2^9
#define IMG_B 32
#define IMG_C 3
#define IMG_H 512
#define IMG_W 512
#define HW_SHIFT 18
#define W_SHIFT 9

#define NBLOCKS_X (IMG_H * IMG_W / 256)   // 1024
#define NPARTIALS (NBLOCKS_X * IMG_B)     // 32768 per-block partial sums

// d_ws layout: [0, 2304)          : 64 inverted 3x3 matrices (32 pred, 32 true), 9 floats each
//              [2304, 2304+128K)  : per-block float partial sums (no atomics)
#define WS_INV_FLOATS (64 * 9)
#define WS_PART_OFFSET (WS_INV_FLOATS * sizeof(float))

__global__ void photoloss_invert_kernel(const float* __restrict__ Hp,
                                        const float* __restrict__ Ht,
                                        float* __restrict__ ws_inv) {
    int t = threadIdx.x;
    if (t < 64) {
        const float* src = (t < 32) ? (Hp + t * 9) : (Ht + (t - 32) * 9);
        float* dst = ws_inv + t * 9;
        // 3x3 inverse via adjugate, computed in double for conditioning
        double a = src[0], b = src[1], c = src[2];
        double d = src[3], e = src[4], f = src[5];
        double g = src[6], h = src[7], i = src[8];
        double A = e * i - f * h;
        double Bc = c * h - b * i;
        double Cc = b * f - c * e;
        double D = f * g - d * i;
        double E = a * i - c * g;
        double F = c * d - a * f;
        double G = d * h - e * g;
        double Hh = b * g - a * h;
        double Ii = a * e - b * d;
        double idet = 1.0 / (a * A + b * D + c * G);
        dst[0] = (float)(A * idet);
        dst[1] = (float)(Bc * idet);
        dst[2] = (float)(Cc * idet);
        dst[3] = (float)(D * idet);
        dst[4] = (float)(E * idet);
        dst[5] = (float)(F * idet);
        dst[6] = (float)(G * idet);
        dst[7] = (float)(Hh * idet);
        dst[8] = (float)(Ii * idet);
    }
}

// Compute clamped flat offset + validity-masked weight for one bilinear corner.
__device__ __forceinline__ void corner(int xi, int yi, float w,
                                       int& off, float& wout) {
    const bool valid = ((unsigned)xi < (unsigned)IMG_W) & ((unsigned)yi < (unsigned)IMG_H);
    const int xc = min(max(xi, 0), IMG_W - 1);
    const int yc = min(max(yi, 0), IMG_H - 1);
    off = (yc << W_SHIFT) + xc;
    wout = valid ? w : 0.0f;
}

__global__ __launch_bounds__(256) void photoloss_main_kernel(
        const float* __restrict__ I,
        const float* __restrict__ ws_inv,
        float* __restrict__ partials) {
    const int b = blockIdx.y;
    const int p = blockIdx.x * 256 + threadIdx.x;  // pixel index within image, < 2^18
    const int y = p >> W_SHIFT;
    const int x = p & (IMG_W - 1);

    const float* __restrict__ hp = ws_inv + b * 9;          // pred inverse
    const float* __restrict__ ht = ws_inv + (b + 32) * 9;   // true inverse

    const float fx = (float)x, fy = (float)y;

    // ---- pred grid ----
    float Xp = hp[0] * fx + hp[1] * fy + hp[2];
    float Yp = hp[3] * fx + hp[4] * fy + hp[5];
    float Zp = hp[6] * fx + hp[7] * fy + hp[8];
    float izp = 1.0f / Zp;
    Xp *= izp; Yp *= izp;
    // reference: x_norm = 2X/(W-1)-1 ; x_pix = ((x_norm+1)*W-1)*0.5
    float xnp = 2.0f * Xp / (float)(IMG_W - 1) - 1.0f;
    float ynp = 2.0f * Yp / (float)(IMG_H - 1) - 1.0f;
    float xsp = ((xnp + 1.0f) * (float)IMG_W - 1.0f) * 0.5f;
    float ysp = ((ynp + 1.0f) * (float)IMG_H - 1.0f) * 0.5f;

    float x0fp = floorf(xsp), y0fp = floorf(ysp);
    int x0p = (int)x0fp, y0p = (int)y0fp;
    int x1p = x0p + 1, y1p = y0p + 1;
    float wx1p = xsp - x0fp, wx0p = 1.0f - wx1p;
    float wy1p = ysp - y0fp, wy0p = 1.0f - wy1p;

    // ---- true grid ----
    float Xt = ht[0] * fx + ht[1] * fy + ht[2];
    float Yt = ht[3] * fx + ht[4] * fy + ht[5];
    float Zt = ht[6] * fx + ht[7] * fy + ht[8];
    float izt = 1.0f / Zt;
    Xt *= izt; Yt *= izt;
    float xnt = 2.0f * Xt / (float)(IMG_W - 1) - 1.0f;
    float ynt = 2.0f * Yt / (float)(IMG_H - 1) - 1.0f;
    float xst = ((xnt + 1.0f) * (float)IMG_W - 1.0f) * 0.5f;
    float yst = ((ynt + 1.0f) * (float)IMG_H - 1.0f) * 0.5f;

    float x0ft = floorf(xst), y0ft = floorf(yst);
    int x0t = (int)x0ft, y0t = (int)y0ft;
    int x1t = x0t + 1, y1t = y0t + 1;
    float wx1t = xst - x0ft, wx0t = 1.0f - wx1t;
    float wy1t = yst - y0ft, wy0t = 1.0f - wy1t;

    // 8 corners: [0..3] = pred (00,10,01,11), [4..7] = true
    int   offs[8];
    float wts[8];
    corner(x0p, y0p, wx0p * wy0p, offs[0], wts[0]);
    corner(x1p, y0p, wx1p * wy0p, offs[1], wts[1]);
    corner(x0p, y1p, wx0p * wy1p, offs[2], wts[2]);
    corner(x1p, y1p, wx1p * wy1p, offs[3], wts[3]);
    corner(x0t, y0t, wx0t * wy0t, offs[4], wts[4]);
    corner(x1t, y0t, wx1t * wy0t, offs[5], wts[5]);
    corner(x0t, y1t, wx0t * wy1t, offs[6], wts[6]);
    corner(x1t, y1t, wx1t * wy1t, offs[7], wts[7]);

    const float* __restrict__ img = I + ((size_t)b * IMG_C << HW_SHIFT);

    // Batch all 24 loads (unconditional, clamped addresses) before any use.
    float v[IMG_C * 8];
#pragma unroll
    for (int c = 0; c < IMG_C; ++c) {
        const float* __restrict__ ch = img + ((size_t)c << HW_SHIFT);
#pragma unroll
        for (int k = 0; k < 8; ++k) {
            v[c * 8 + k] = ch[offs[k]];
        }
    }

    float lsum = 0.0f;
#pragma unroll
    for (int c = 0; c < IMG_C; ++c) {
        const float* vc = v + c * 8;
        float vp = vc[0] * wts[0] + vc[1] * wts[1] + vc[2] * wts[2] + vc[3] * wts[3];
        float vt = vc[4] * wts[4] + vc[5] * wts[5] + vc[6] * wts[6] + vc[7] * wts[7];
        float d = vp - vt;
        lsum += d * d;
    }

    // wave (64-lane) reduction
#pragma unroll
    for (int off = 32; off > 0; off >>= 1)
        lsum += __shfl_down(lsum, off, 64);

    __shared__ float wsum[4];
    const int lane = threadIdx.x & 63;
    const int wid = threadIdx.x >> 6;
    if (lane == 0) wsum[wid] = lsum;
    __syncthreads();
    if (threadIdx.x == 0) {
        // One coalesced store per block -- NO atomics (same-address fp64
        // atomicAdd serialized the whole grid at ~400 us in R1/R2).
        partials[blockIdx.y * gridDim.x + blockIdx.x] = wsum[0] + wsum[1] + wsum[2] + wsum[3];
    }
}

__global__ __launch_bounds__(1024) void photoloss_reduce_kernel(
        const float* __restrict__ partials, float* __restrict__ out) {
    // Single block, 1024 threads = 16 waves; 32 partials per thread.
    double s = 0.0;
    for (int i = threadIdx.x; i < NPARTIALS; i += 1024)
        s += (double)partials[i];
#pragma unroll
    for (int off = 32; off > 0; off >>= 1)
        s += __shfl_down(s, off, 64);

    __shared__ double wsum[16];
    const int lane = threadIdx.x & 63;
    const int wid = threadIdx.x >> 6;
    if (lane == 0) wsum[wid] = s;
    __syncthreads();
    if (threadIdx.x == 0) {
        double total = 0.0;
#pragma unroll
        for (int i = 0; i < 16; ++i) total += wsum[i];
        const double n = (double)IMG_B * IMG_C * IMG_H * IMG_W;  // 25165824
        out[0] = (float)(total / n);
    }
}

extern "C" void kernel_launch(void* const* d_in, const int* in_sizes, int n_in,
                              void* d_out, int out_size, void* d_ws, size_t ws_size,
                              hipStream_t stream) {
    const float* Hp = (const float*)d_in[0];
    const float* Ht = (const float*)d_in[1];
    const float* I  = (const float*)d_in[2];
    float* out = (float*)d_out;

    float* ws_inv = (float*)d_ws;
    float* partials = (float*)((char*)d_ws + WS_PART_OFFSET);

    photoloss_invert_kernel<<<1, 64, 0, stream>>>(Hp, Ht, ws_inv);

    dim3 grid(NBLOCKS_X, IMG_B);  // (1024, 32)
    photoloss_main_kernel<<<grid, 256, 0, stream>>>(I, ws_inv, partials);

    photoloss_reduce_kernel<<<1, 1024, 0, stream>>>(partials, out);
}

// Round 5
// 233.548 us; speedup vs baseline: 2.2911x; 1.0121x over previous
//
#include <hip/hip_runtime.h>

// Problem constants (powers of two -> shift/mask index math)
// B=32, C=3, H=512, W=512; H*W = 2^18, W = 2^9
#define IMG_B 32
#define IMG_C 3
#define IMG_H 512
#define IMG_W 512
#define HW_SHIFT 18
#define W_SHIFT 9

#define NBLOCKS_X (IMG_H * IMG_W / 256)   // 1024
#define NPARTIALS (NBLOCKS_X * IMG_B)     // 32768 per-block partial sums

// d_ws layout: [0, 2304)          : 64 inverted 3x3 matrices (32 pred, 32 true), 9 floats each
//                                   rows 0/1 pre-scaled by 512/511 (normalization folded in)
//              [2304, 2304+128K)  : per-block float partial sums (no atomics)
#define WS_INV_FLOATS (64 * 9)
#define WS_PART_OFFSET (WS_INV_FLOATS * sizeof(float))

__global__ void photoloss_invert_kernel(const float* __restrict__ Hp,
                                        const float* __restrict__ Ht,
                                        float* __restrict__ ws_inv) {
    int t = threadIdx.x;
    if (t < 64) {
        const float* src = (t < 32) ? (Hp + t * 9) : (Ht + (t - 32) * 9);
        float* dst = ws_inv + t * 9;
        // 3x3 inverse via adjugate, computed in double for conditioning.
        double a = src[0], b = src[1], c = src[2];
        double d = src[3], e = src[4], f = src[5];
        double g = src[6], h = src[7], i = src[8];
        double A = e * i - f * h;
        double Bc = c * h - b * i;
        double Cc = b * f - c * e;
        double D = f * g - d * i;
        double E = a * i - c * g;
        double F = c * d - a * f;
        double G = d * h - e * g;
        double Hh = b * g - a * h;
        double Ii = a * e - b * d;
        double idet = 1.0 / (a * A + b * D + c * G);
        // Fold the grid-normalization chain into rows 0/1:
        // xs = ((2X/(W-1)-1+1)*W-1)*0.5 = X*(W/(W-1)) - 0.5
        const double sc = (double)IMG_W / (double)(IMG_W - 1);  // 512/511 (H==W)
        dst[0] = (float)(A * idet * sc);
        dst[1] = (float)(Bc * idet * sc);
        dst[2] = (float)(Cc * idet * sc);
        dst[3] = (float)(D * idet * sc);
        dst[4] = (float)(E * idet * sc);
        dst[5] = (float)(F * idet * sc);
        dst[6] = (float)(G * idet);
        dst[7] = (float)(Hh * idet);
        dst[8] = (float)(Ii * idet);
    }
}

// One grid's sampling setup: 4 clamped byte offsets + 4 masked corner weights.
// Validity lives ONLY in the weights (per-axis select to exact 0.0f); offsets
// are clamped to [0, 2^19] so the buffer bounds check handles y-overflow
// (off*4 >= 2^20 -> returns 0) and no 32-bit wrap is possible.
__device__ __forceinline__ void grid_setup(float X, float Y, float Z,
                                           int* voff, float* w) {
    const float iz = __builtin_amdgcn_rcpf(Z);
    const float xs = __builtin_fmaf(X, iz, -0.5f);
    const float ys = __builtin_fmaf(Y, iz, -0.5f);

    const float x0f = __builtin_floorf(xs);
    const float y0f = __builtin_floorf(ys);
    const int x0 = (int)x0f, y0 = (int)y0f;
    const int x1 = (int)((unsigned)x0 + 1u);
    const int y1 = (int)((unsigned)y0 + 1u);

    float wx1 = xs - x0f, wx0 = 1.0f - wx1;
    float wy1 = ys - y0f, wy0 = 1.0f - wy1;
    // per-axis validity masking (select, not multiply: kills NaN/Inf cases too)
    wx0 = ((unsigned)x0 < (unsigned)IMG_W) ? wx0 : 0.0f;
    wx1 = ((unsigned)x1 < (unsigned)IMG_W) ? wx1 : 0.0f;
    wy0 = ((unsigned)y0 < (unsigned)IMG_H) ? wy0 : 0.0f;
    wy1 = ((unsigned)y1 < (unsigned)IMG_H) ? wy1 : 0.0f;

    w[0] = wx0 * wy0; w[1] = wx1 * wy0; w[2] = wx0 * wy1; w[3] = wx1 * wy1;

    const int base00 = (y0 << W_SHIFT) + x0;  // may wrap; clamped below
    const int lim = 1 << 19;
    int o00 = min(max(base00, 0), lim);
    int o10 = min(max(base00 + 1, 0), lim);
    int o01 = min(max(base00 + IMG_W, 0), lim);
    int o11 = min(max(base00 + IMG_W + 1, 0), lim);
    voff[0] = o00 << 2; voff[1] = o10 << 2; voff[2] = o01 << 2; voff[3] = o11 << 2;
}

__device__ __forceinline__ float buf_load_f32(__amdgpu_buffer_rsrc_t srd, int voff) {
    int r = __builtin_amdgcn_raw_buffer_load_b32(srd, voff, 0, 0);
    return __builtin_bit_cast(float, r);
}

__global__ __launch_bounds__(256) void photoloss_main_kernel(
        const float* __restrict__ I,
        const float* __restrict__ ws_inv,
        float* __restrict__ partials) {
    const int b = blockIdx.y;
    const int p = blockIdx.x * 256 + threadIdx.x;  // pixel index within image
    const float fx = (float)(p & (IMG_W - 1));
    const float fy = (float)(p >> W_SHIFT);

    const float* __restrict__ hp = ws_inv + b * 9;          // pred inverse (rows 0/1 pre-scaled)
    const float* __restrict__ ht = ws_inv + (b + 32) * 9;   // true inverse

    // homography transforms (rows 0/1 carry the 512/511 normalization scale)
    const float Xp = __builtin_fmaf(hp[0], fx, __builtin_fmaf(hp[1], fy, hp[2]));
    const float Yp = __builtin_fmaf(hp[3], fx, __builtin_fmaf(hp[4], fy, hp[5]));
    const float Zp = __builtin_fmaf(hp[6], fx, __builtin_fmaf(hp[7], fy, hp[8]));
    const float Xt = __builtin_fmaf(ht[0], fx, __builtin_fmaf(ht[1], fy, ht[2]));
    const float Yt = __builtin_fmaf(ht[3], fx, __builtin_fmaf(ht[4], fy, ht[5]));
    const float Zt = __builtin_fmaf(ht[6], fx, __builtin_fmaf(ht[7], fy, ht[8]));

    int   voff[8];
    float wts[8];
    grid_setup(Xp, Yp, Zp, voff,     wts);
    grid_setup(Xt, Yt, Zt, voff + 4, wts + 4);

    const float* __restrict__ img = I + ((size_t)b * IMG_C << HW_SHIFT);
    // SRD per channel (2^20 bytes each). OOB voffset -> load returns 0.
    __amdgpu_buffer_rsrc_t srd0 = __builtin_amdgcn_make_buffer_rsrc(
        (void*)(img + ((size_t)0 << HW_SHIFT)), (short)0, IMG_H * IMG_W * 4, 0x00020000);
    __amdgpu_buffer_rsrc_t srd1 = __builtin_amdgcn_make_buffer_rsrc(
        (void*)(img + ((size_t)1 << HW_SHIFT)), (short)0, IMG_H * IMG_W * 4, 0x00020000);
    __amdgpu_buffer_rsrc_t srd2 = __builtin_amdgcn_make_buffer_rsrc(
        (void*)(img + ((size_t)2 << HW_SHIFT)), (short)0, IMG_H * IMG_W * 4, 0x00020000);

    // Batch all 24 buffer loads (one 32-bit voffset per corner, shared across
    // channels; SRD is SGPR) before any use.
    float v[IMG_C * 8];
#pragma unroll
    for (int k = 0; k < 8; ++k) v[0 * 8 + k] = buf_load_f32(srd0, voff[k]);
#pragma unroll
    for (int k = 0; k < 8; ++k) v[1 * 8 + k] = buf_load_f32(srd1, voff[k]);
#pragma unroll
    for (int k = 0; k < 8; ++k) v[2 * 8 + k] = buf_load_f32(srd2, voff[k]);

    float lsum = 0.0f;
#pragma unroll
    for (int c = 0; c < IMG_C; ++c) {
        const float* vc = v + c * 8;
        float vp = vc[0] * wts[0] + vc[1] * wts[1] + vc[2] * wts[2] + vc[3] * wts[3];
        float vt = vc[4] * wts[4] + vc[5] * wts[5] + vc[6] * wts[6] + vc[7] * wts[7];
        float d = vp - vt;
        lsum = __builtin_fmaf(d, d, lsum);
    }

    // wave (64-lane) reduction
#pragma unroll
    for (int off = 32; off > 0; off >>= 1)
        lsum += __shfl_down(lsum, off, 64);

    __shared__ float wsum[4];
    const int lane = threadIdx.x & 63;
    const int wid = threadIdx.x >> 6;
    if (lane == 0) wsum[wid] = lsum;
    __syncthreads();
    if (threadIdx.x == 0) {
        // One coalesced store per block -- NO atomics (same-address fp64
        // atomicAdd serialized the whole grid at ~400 us in R1/R2).
        partials[blockIdx.y * gridDim.x + blockIdx.x] = wsum[0] + wsum[1] + wsum[2] + wsum[3];
    }
}

__global__ __launch_bounds__(1024) void photoloss_reduce_kernel(
        const float* __restrict__ partials, float* __restrict__ out) {
    // Single block, 1024 threads = 16 waves; 32 partials per thread.
    double s = 0.0;
    for (int i = threadIdx.x; i < NPARTIALS; i += 1024)
        s += (double)partials[i];
#pragma unroll
    for (int off = 32; off > 0; off >>= 1)
        s += __shfl_down(s, off, 64);

    __shared__ double wsum[16];
    const int lane = threadIdx.x & 63;
    const int wid = threadIdx.x >> 6;
    if (lane == 0) wsum[wid] = s;
    __syncthreads();
    if (threadIdx.x == 0) {
        double total = 0.0;
#pragma unroll
        for (int i = 0; i < 16; ++i) total += wsum[i];
        const double n = (double)IMG_B * IMG_C * IMG_H * IMG_W;  // 25165824
        out[0] = (float)(total / n);
    }
}

extern "C" void kernel_launch(void* const* d_in, const int* in_sizes, int n_in,
                              void* d_out, int out_size, void* d_ws, size_t ws_size,
                              hipStream_t stream) {
    const float* Hp = (const float*)d_in[0];
    const float* Ht = (const float*)d_in[1];
    const float* I  = (const float*)d_in[2];
    float* out = (float*)d_out;

    float* ws_inv = (float*)d_ws;
    float* partials = (float*)((char*)d_ws + WS_PART_OFFSET);

    photoloss_invert_kernel<<<1, 64, 0, stream>>>(Hp, Ht, ws_inv);

    dim3 grid(NBLOCKS_X, IMG_B);  // (1024, 32)
    photoloss_main_kernel<<<grid, 256, 0, stream>>>(I, ws_inv, partials);

    photoloss_reduce_kernel<<<1, 1024, 0, stream>>>(partials, out);
}